// Round 5
// baseline (314.693 us; speedup 1.0000x reference)
//
#include <hip/hip_runtime.h>

// Frobenius — R14: self-tagged data words; rendezvous = ONE fabric hop.
//
// Ladder: R9 181 -> R11 166.6 -> R13 160.4 (R10/R12 regressions).
// R13 post-mortem: per-iter ~7 us, ~2.5 us VALU, rest = rendezvous serial
// hops: store -> vmcnt(0) remote-ack -> A2 -> flag store -> flag propagate ->
// poll -> data RTT. Three cross-fabric latencies even with hoisted gathers.
// Plus 655K LDS bank conflicts from the tail's scalar rqf reads.
//
// R14: every published word is (tag<<32 | f32 bits); consumers poll the DATA
// for the tag. Deletes the drain (no release flag to order), the A2 barrier,
// the flag hop, and the data RTT (poll success == datum in register).
//   pre-A1 (wave-local): col partial cqA; part transpose; row fold; publish
//     rowF[256 tagged words/block]; per-wave blocksum butterfly -> sbsL.
//   A1.
//   wave0: fold cqA -> publish colF[256 tagged]; wave1: fold sbsL -> publish
//     gsB[1 tagged, 64B-spaced] — in parallel. No drain, no flag.
//   polls: rows -> register xor-butterfly over 16 peers (NO LDS -> kills the
//     655K conflicts); cols -> park in cqB; gsB -> bsv (t<256, one
//     poller/word on spaced lines = R11's proven contention density).
//   B0; tail: col fold (16 conflict-free v4 reads), sG butterfly, row
//     broadcast via shfl, update. 2 barriers/iter total.
//
// Correctness:
//  - b64 atomic load/store are single-copy atomic: tag+payload move together
//    (the R8 lesson's primitive).
//  - Exact-tag polls + parity double-buffer: a k+2 overwrite (same parity)
//    carries tag k+3 != k+1, and can only be ISSUED after its producer
//    gathered all k+1 data (values feed x(k+2) by dataflow), which required
//    every block's k+1 publishes, which data-depend on those blocks' k
//    gathers -> no writer can clobber a word a reader still needs.
//  - Stale tags from a PREVIOUS launch (1..20 alias) are destroyed by the
//    in-stream memset of all tagged arrays (2.1 MB, replay-safe; harness
//    0xAA poison gives tag 0xAAAAAAAA which never matches).

#define NN    4096
#define NV4   1024
#define NBLK  256
#define ITERS 20
#define INV_N (1.0f / 4096.0f)

typedef unsigned long long u64;
typedef float f32x4 __attribute__((ext_vector_type(4)));

__device__ __forceinline__ float wave_reduce_sum(float v) {
    #pragma unroll
    for (int m = 1; m < 64; m <<= 1) v += __shfl_xor(v, m, 64);
    return v;
}
__device__ __forceinline__ void st_b64(u64* p, u64 v) {
    __hip_atomic_store(p, v, __ATOMIC_RELAXED, __HIP_MEMORY_SCOPE_AGENT);
}
__device__ __forceinline__ u64 ld_b64(const u64* p) {
    return __hip_atomic_load(p, __ATOMIC_RELAXED, __HIP_MEMORY_SCOPE_AGENT);
}
__device__ __forceinline__ u64 tagf(u64 tagv, float x) {
    return (tagv << 32) | (u64)__float_as_uint(x);
}
__device__ __forceinline__ float lo32(u64 u) { return __uint_as_float((unsigned)u); }

// Poll 4 consecutive tagged words; all 4 loads issued back-to-back so their
// latencies overlap. Returns payloads once every tag matches.
__device__ __forceinline__ f32x4 poll_quad(const u64* p, u64 tagv) {
    u64 a = ld_b64(p), b = ld_b64(p + 1), c = ld_b64(p + 2), d = ld_b64(p + 3);
    while (((a >> 32) != tagv) | ((b >> 32) != tagv) |
           ((c >> 32) != tagv) | ((d >> 32) != tagv)) {
        __builtin_amdgcn_s_sleep(1);
        a = ld_b64(p); b = ld_b64(p + 1); c = ld_b64(p + 2); d = ld_b64(p + 3);
    }
    f32x4 r; r.x = lo32(a); r.y = lo32(b); r.z = lo32(c); r.w = lo32(d);
    return r;
}

__global__ __launch_bounds__(1024, 4)
void persist13(const float* __restrict__ X0, float* __restrict__ Xout,
               u64* __restrict__ colF,   // [2][256][256] tagged col partials
               u64* __restrict__ rowF,   // [2][256][256] tagged row partials
               u64* __restrict__ gsB)    // [2][256] stride-8 tagged blocksums
{
    const int t    = threadIdx.x;
    const int lane = t & 63;
    const int g    = t >> 6;          // wave = 16-row group
    const int c    = lane;            // 4-col quad
    const int b    = blockIdx.x;
    const int bi   = b >> 4;
    const int bj   = b & 15;

    // ~103.5 KB -> 1 block/CU (grid == 256 == #CUs) -> co-residency.
    __shared__ float part[16][64][17];   // row-partial transpose (69.6 KB)
    __shared__ f32x4 cqA[16][64];        // phase-A col partials (16 KB)
    __shared__ f32x4 cqB[16][64];        // gathered col partials (16 KB)
    __shared__ float sbsL[16];           // per-wave blocksum shares
    __shared__ float bsv[256];           // peer blocksums

    f32x4 x[16];
    {
        const f32x4* xi = (const f32x4*)X0;
        const size_t base = (size_t)(bi * 256 + g * 16) * NV4 + (bj * 64 + c);
        #pragma unroll
        for (int r = 0; r < 16; ++r)
            x[r] = xi[base + (size_t)r * NV4];
    }

    for (int iter = 0; iter < ITERS; ++iter) {
        const int p = iter & 1;
        const u64 tagv = (u64)(iter + 1);

        // ---- pre-A1: wave-local partials; publish rows + blocksum share
        f32x4 cacc = x[0];
        #pragma unroll
        for (int r = 1; r < 16; ++r) cacc += x[r];
        cqA[g][c] = cacc;                             // per-wave col partial
        #pragma unroll
        for (int r = 0; r < 16; ++r)                  // 17-pad: 2-way max
            part[g][c][r] = (x[r].x + x[r].y) + (x[r].z + x[r].w);
        asm volatile("s_waitcnt lgkmcnt(0)" ::: "memory");  // wave-local LDS
        float v;
        {   // row fold: wave g's 16 rows over 64 col-quads (LDS transpose)
            const int r_ = lane & 15, q_ = lane >> 4;
            v = 0.f;
            #pragma unroll
            for (int k = 0; k < 16; ++k) v += part[g][q_ * 16 + k][r_];
            v += __shfl_xor(v, 16, 64);
            v += __shfl_xor(v, 32, 64);   // all lanes: rowsum[16g + (lane&15)]
        }
        if (lane < 16)                    // 16 consecutive b64 = 128 B
            st_b64(rowF + (((size_t)(p * NBLK + b)) << 8) + 16 * g + lane,
                   tagf(tagv, v));
        {   // wave-band blocksum share (butterfly over the 16 row classes)
            float v2 = v;
            v2 += __shfl_xor(v2, 1, 64); v2 += __shfl_xor(v2, 2, 64);
            v2 += __shfl_xor(v2, 4, 64); v2 += __shfl_xor(v2, 8, 64);
            if (lane == 0) sbsL[g] = v2;
        }
        __syncthreads();                              // A1

        // ---- post-A1 publishes (parallel, no drain, no flag)
        if (g == 0) {        // col fold over 16 waves -> 4 tagged words/lane
            f32x4 vq = cqA[0][c];
            #pragma unroll
            for (int k = 1; k < 16; ++k) vq += cqA[k][c];
            u64* dst = colF + (((size_t)(p * NBLK + b)) << 8) + 4 * c;
            st_b64(dst,     tagf(tagv, vq.x));
            st_b64(dst + 1, tagf(tagv, vq.y));
            st_b64(dst + 2, tagf(tagv, vq.z));
            st_b64(dst + 3, tagf(tagv, vq.w));
        } else if (g == 1) { // blocksum fold -> 1 tagged word (64B-spaced)
            float sv = sbsL[lane & 15];
            sv += __shfl_xor(sv, 1, 64); sv += __shfl_xor(sv, 2, 64);
            sv += __shfl_xor(sv, 4, 64); sv += __shfl_xor(sv, 8, 64);
            if (lane == 0)
                st_b64(gsB + ((size_t)(p * NBLK + b) << 3), tagf(tagv, sv));
        }

        // ---- polls: data IS the signal (one fabric hop)
        f32x4 rq;   // folded row quads, register-only (no LDS, no conflicts)
        {   // lane l: peer j=l>>2 (row band), rows 16g+4*(l&3)..+3
            const int j = lane >> 2, rqi = lane & 3;
            const u64* rp = rowF + (((size_t)(p * NBLK + bi * 16 + j)) << 8)
                                 + 16 * g + 4 * rqi;
            f32x4 rv = poll_quad(rp, tagv);
            #pragma unroll
            for (int m = 4; m <= 32; m <<= 1) {       // fold 16 peers
                rv.x += __shfl_xor(rv.x, m, 64);
                rv.y += __shfl_xor(rv.y, m, 64);
                rv.z += __shfl_xor(rv.z, m, 64);
                rv.w += __shfl_xor(rv.w, m, 64);
            }
            rq = rv;   // lane l holds rows 16g+4*(l&3)..+3, folded
        }
        {   // col gather: wave g takes peer g*16+bj, park in LDS
            const u64* cp = colF + (((size_t)(p * NBLK + g * 16 + bj)) << 8) + 4 * c;
            cqB[g][c] = poll_quad(cp, tagv);
        }
        if (t < 256) {       // blocksums: one poller per word, spaced lines
            const u64* gp = gsB + ((size_t)(p * NBLK + t) << 3);
            u64 u = ld_b64(gp);
            while ((u >> 32) != tagv) {
                __builtin_amdgcn_s_sleep(1);
                u = ld_b64(gp);
            }
            bsv[t] = lo32(u);
        }
        asm volatile("" ::: "memory");
        __syncthreads();                              // B0

        // ---- tail: conflict-free folds, register row broadcast
        f32x4 cs = cqB[0][c];
        #pragma unroll
        for (int k = 1; k < 16; ++k) cs += cqB[k][c]; // consecutive v4: free
        float vb = bsv[lane] + bsv[64 + lane] + bsv[128 + lane] + bsv[192 + lane];
        const float sG = wave_reduce_sum(vb);         // identical all blocks

        const float cc0 = INV_N + sG * (INV_N * INV_N);
        const f32x4 csub = cs * INV_N;
        const float rqa[4] = {rq.x, rq.y, rq.z, rq.w};
        #pragma unroll
        for (int r = 0; r < 16; ++r) {
            // rowsum[16g+r]: component r&3 of lane (r>>2)'s folded quad
            const float rwr = __shfl(rqa[r & 3], r >> 2, 64);
            const float a = cc0 - rwr * INV_N;
            x[r].x = fmaxf(x[r].x + a - csub.x, 0.f);
            x[r].y = fmaxf(x[r].y + a - csub.y, 0.f);
            x[r].z = fmaxf(x[r].z + a - csub.z, 0.f);
            x[r].w = fmaxf(x[r].w + a - csub.w, 0.f);
        }
        // LDS reuse across iters: k-tail reads precede A1(k+1); k+1 writes
        // to cqB/bsv are post-A1(k+1), to cqA/part/sbsL pre-A1(k+1) but
        // ordered after k-tail reads by B0(k) in each thread's program order
        // + A1 barrier semantics (writers of cqA(k+1) passed B0(k) too).
    }

    {   // final store (plain cached path)
        f32x4* xo = (f32x4*)Xout;
        const size_t base = (size_t)(bi * 256 + g * 16) * NV4 + (bj * 64 + c);
        #pragma unroll
        for (int r = 0; r < 16; ++r)
            xo[base + (size_t)r * NV4] = x[r];
    }
}

extern "C" void kernel_launch(void* const* d_in, const int* in_sizes, int n_in,
                              void* d_out, int out_size, void* d_ws, size_t ws_size,
                              hipStream_t stream)
{
    const float* X0 = (const float*)d_in[0];
    float* X = (float*)d_out;

    // ws: colF 1 MB | rowF 1 MB | gsB 32 KB  (contiguous, ~2.06 MB)
    u64* colF = (u64*)d_ws;
    u64* rowF = colF + 2 * NBLK * 256;
    u64* gsB  = rowF + 2 * NBLK * 256;

    // Memset ALL tagged arrays: kills stale 1..20 tags from a previous
    // launch (replay-safe: the memset is part of the captured stream).
    const size_t tagged_bytes =
        (size_t)(2 * NBLK * 256 + 2 * NBLK * 256 + 2 * NBLK * 8) * sizeof(u64);
    hipMemsetAsync((void*)colF, 0, tagged_bytes, stream);

    // ~103.5 KB LDS -> 1 block/CU; grid == CU count -> all 256 blocks
    // co-resident (spin-waits are deadlock-free).
    persist13<<<dim3(NBLK), dim3(1024), 0, stream>>>(X0, X, colF, rowF, gsB);
}

// Round 6
// 279.070 us; speedup vs baseline: 1.1276x; 1.1276x over previous
//
#include <hip/hip_runtime.h>

// Frobenius — R15: R13 structure (proven 160.4 us) minus the flag-edge
// drain: self-tagged data words, flag-after-stores in program order.
//
// Ladder: R9 181 -> R11 166.6 -> R13 160.4 (best). R10 188 / R12 200 /
// R14 289 REGRESSIONS.
// R14 post-mortem (law, confirmed 2x by R10+R14): poll density must stay
// <=256 pollers/block on dedicated 64B-spaced lines, wave-uniform where
// possible. Polling DATA words (each consumer spinning on 8 remote u64)
// saturates the fabric and delays the very stores being polled.
//
// R15 delta vs R13 (everything else verbatim):
//  - colF/rowF words self-tagged (tag<<32 | f32 bits, b64 single-copy
//    atomic). gsB = spaced flag word, payload = blocksum (as R13's pflag).
//  - rowF published PRE-A1 (wave-local row fold) -> long landed by poll.
//  - NO vmcnt(0) drain, NO A2 barrier: wave0 folds cqA post-A1, issues 4
//    tagged colF stores, butterflies the blocksum, lane0 stores gsB.
//    Program order (same wave, same VMEM pipe) => flag trails data on the
//    fabric by ~the butterfly latency; rowF trails by the whole row fold.
//  - Consumers WAIT only on gsB lines (R13's fused fc/fr/fb poll, proven
//    density); gathers are one-shot loads that VERIFY tags and retry only
//    stragglers (expected ~0 retries).
//
// WAR safety (parity double-buffer, no drain needed): block B writes
// parity-p words for iter k+2 only after its iter-k+1 poll observed ALL
// gsB at tag k+2; gsB[j]@k+2 is stored after j's A1(k+1), which follows
// j's iter-k gathers in program order -> no overwrite of live data.
// Payload dataflow (x(k+2) depends on gathered k+1 data) keeps the
// hardware from issuing k+2 publishes early.
//
// Stale tags from a previous launch (1..20 alias) are destroyed by the
// in-stream memset of all tagged arrays (~2 MB, graph-replay-safe).

#define NN    4096
#define NV4   1024
#define NBLK  256
#define ITERS 20
#define INV_N (1.0f / 4096.0f)

typedef unsigned long long u64;
typedef float f32x4 __attribute__((ext_vector_type(4)));

__device__ __forceinline__ float wave_reduce_sum(float v) {
    #pragma unroll
    for (int m = 1; m < 64; m <<= 1) v += __shfl_xor(v, m, 64);
    return v;
}
__device__ __forceinline__ void st_b64(u64* p, u64 v) {
    __hip_atomic_store(p, v, __ATOMIC_RELAXED, __HIP_MEMORY_SCOPE_AGENT);
}
__device__ __forceinline__ u64 ld_b64(const u64* p) {
    return __hip_atomic_load(p, __ATOMIC_RELAXED, __HIP_MEMORY_SCOPE_AGENT);
}
__device__ __forceinline__ u64 tagf(u64 tagv, float x) {
    return (tagv << 32) | (u64)__float_as_uint(x);
}
__device__ __forceinline__ float lo32(u64 u) { return __uint_as_float((unsigned)u); }

// One-shot gather of 4 tagged words; retries only if a tag hasn't landed
// (rare: producers' data stores precede the polled flag in issue order).
__device__ __forceinline__ f32x4 gather_quad(const u64* p, u64 tagv) {
    u64 a = ld_b64(p), b = ld_b64(p + 1), c = ld_b64(p + 2), d = ld_b64(p + 3);
    while (((a >> 32) != tagv) | ((b >> 32) != tagv) |
           ((c >> 32) != tagv) | ((d >> 32) != tagv)) {
        __builtin_amdgcn_s_sleep(1);
        a = ld_b64(p); b = ld_b64(p + 1); c = ld_b64(p + 2); d = ld_b64(p + 3);
    }
    f32x4 r; r.x = lo32(a); r.y = lo32(b); r.z = lo32(c); r.w = lo32(d);
    return r;
}

__global__ __launch_bounds__(1024, 4)
void persist14(const float* __restrict__ X0, float* __restrict__ Xout,
               u64* __restrict__ colF,   // [2][256][256] tagged col partials
               u64* __restrict__ rowF,   // [2][256][256] tagged row partials
               u64* __restrict__ gsB)    // [2][256] stride-8: flag+blocksum
{
    const int t    = threadIdx.x;
    const int lane = t & 63;
    const int g    = t >> 6;          // wave = 16-row group
    const int c    = lane;            // 4-col quad
    const int b    = blockIdx.x;
    const int bi   = b >> 4;
    const int bj   = b & 15;

    // ~118.7 KB -> 1 block/CU (grid == 256 == #CUs) -> co-residency.
    __shared__ float part[16][64][17];   // row-partial transpose (69.6 KB)
    __shared__ f32x4 cqA[16][64];        // phase-A col partials (16 KB)
    __shared__ f32x4 cqB[16][64];        // gathered col partials (16 KB)
    __shared__ f32x4 rqB[16][64];        // gathered row partials (16 KB)
    __shared__ float bsv[256];           // peer blocksums (1 KB)

    f32x4 x[16];
    {
        const f32x4* xi = (const f32x4*)X0;
        const size_t base = (size_t)(bi * 256 + g * 16) * NV4 + (bj * 64 + c);
        #pragma unroll
        for (int r = 0; r < 16; ++r)
            x[r] = xi[base + (size_t)r * NV4];
    }

    for (int iter = 0; iter < ITERS; ++iter) {
        const int p = iter & 1;
        const u64 tagv = (u64)(iter + 1);

        // ---- pre-A1: wave-local partials; publish tagged rowF early
        f32x4 cacc = x[0];
        #pragma unroll
        for (int r = 1; r < 16; ++r) cacc += x[r];
        cqA[g][c] = cacc;                             // per-wave col partial
        #pragma unroll
        for (int r = 0; r < 16; ++r)                  // 17-pad: 2-way max
            part[g][c][r] = (x[r].x + x[r].y) + (x[r].z + x[r].w);
        asm volatile("s_waitcnt lgkmcnt(0)" ::: "memory");  // wave-local LDS
        {   // row fold: wave g's 16 rows over 64 col-quads (LDS transpose)
            const int r_ = lane & 15, q_ = lane >> 4;
            float v = 0.f;
            #pragma unroll
            for (int k = 0; k < 16; ++k) v += part[g][q_ * 16 + k][r_];
            v += __shfl_xor(v, 16, 64);
            v += __shfl_xor(v, 32, 64);   // all lanes: rowsum[16g+(lane&15)]
            if (lane < 16)                // 16 consecutive tagged words
                st_b64(rowF + (((size_t)(p * NBLK + b)) << 8) + 16 * g + lane,
                       tagf(tagv, v));
        }
        __syncthreads();                              // A1

        // ---- post-A1: wave0 publishes colF then the flag (program order,
        //      NO drain, NO second barrier)
        if (g == 0) {
            f32x4 vq = cqA[0][c];
            #pragma unroll
            for (int k = 1; k < 16; ++k) vq += cqA[k][c];
            u64* dst = colF + (((size_t)(p * NBLK + b)) << 8) + 4 * c;
            st_b64(dst,     tagf(tagv, vq.x));
            st_b64(dst + 1, tagf(tagv, vq.y));
            st_b64(dst + 2, tagf(tagv, vq.z));
            st_b64(dst + 3, tagf(tagv, vq.w));
            float bs = wave_reduce_sum((vq.x + vq.y) + (vq.z + vq.w));
            asm volatile("" ::: "memory");   // keep colF stores before flag
            if (lane == 0)
                st_b64(gsB + ((size_t)(p * NBLK + b) << 3), tagf(tagv, bs));
        }

        // ---- phase B: R13's fused poll on spaced gsB lines (proven density)
        const int fcsrc = g * 16 + bj;    // col producer (wave-uniform)
        const int frsrc = bi * 16 + g;    // row producer (wave-uniform)
        {
            const u64* fc = gsB + ((size_t)(p * NBLK + fcsrc) << 3);
            const u64* fr = gsB + ((size_t)(p * NBLK + frsrc) << 3);
            const u64* fb = gsB + ((size_t)(p * NBLK + (t & 255)) << 3);
            bool dc = false, dr = false, db = (t >= 256);
            u64 ub = 0;
            // loop 1: wait for this wave's two producers (bsv opportunistic)
            while (!(dc && dr)) {
                if (!dc && (ld_b64(fc) >> 32) == tagv) dc = true;
                if (!dr && (ld_b64(fr) >> 32) == tagv) dr = true;
                if (!db) { u64 u = ld_b64(fb);
                           if ((u >> 32) == tagv) { ub = u; db = true; } }
                if (!(dc && dr)) __builtin_amdgcn_s_sleep(1);
            }
            asm volatile("" ::: "memory");
            {   // one-shot tagged gathers (rare retry), park in LDS
                const u64* cp = colF + (((size_t)(p * NBLK + fcsrc)) << 8) + 4 * c;
                const u64* rp = rowF + (((size_t)(p * NBLK + frsrc)) << 8) + 4 * c;
                cqB[g][c] = gather_quad(cp, tagv);
                rqB[g][c] = gather_quad(rp, tagv);
            }
            // loop 2: finish the bsv poll (t<256 lanes only)
            while (!db) {
                u64 u = ld_b64(fb);
                if ((u >> 32) == tagv) { ub = u; db = true; }
                else __builtin_amdgcn_s_sleep(1);
            }
            if (t < 256) bsv[t] = lo32(ub);
        }
        asm volatile("" ::: "memory");
        __syncthreads();    // B0: all gathers in LDS, bsv complete

        // ---- tail (R13 verbatim): redundant per-wave/per-thread folds
        float vb = bsv[lane] + bsv[64 + lane] + bsv[128 + lane] + bsv[192 + lane];
        const float sG = wave_reduce_sum(vb);
        f32x4 cs = cqB[0][c];
        #pragma unroll
        for (int k = 1; k < 16; ++k) cs += cqB[k][c];
        float vr;
        {
            const int rr = lane & 15, kk = lane >> 4;
            const float* rqf = (const float*)&rqB[0][0];
            vr = 0.f;
            #pragma unroll
            for (int j = 0; j < 4; ++j)
                vr += rqf[(((4 * kk + j) * 64) + (4 * g + (rr >> 2))) * 4 + (rr & 3)];
            vr += __shfl_xor(vr, 16, 64);
            vr += __shfl_xor(vr, 32, 64);   // lane class rr holds rowsum[16g+rr]
        }

        const float cc0 = INV_N + sG * (INV_N * INV_N);
        const f32x4 csub = cs * INV_N;
        #pragma unroll
        for (int r = 0; r < 16; ++r) {
            const float rwr = __shfl(vr, r, 64);      // rowsum[16g+r]
            const float a = cc0 - rwr * INV_N;
            x[r].x = fmaxf(x[r].x + a - csub.x, 0.f);
            x[r].y = fmaxf(x[r].y + a - csub.y, 0.f);
            x[r].z = fmaxf(x[r].z + a - csub.z, 0.f);
            x[r].w = fmaxf(x[r].w + a - csub.w, 0.f);
        }
        // LDS reuse: iter-k tail reads precede A1(k+1); k+1 writes to
        // cqB/rqB/bsv are post-A1(k+1); cqA/part writes of k+1 are pre-A1
        // but each thread passed B0(k) first (program order) -> race-free.
    }

    {   // final store (plain cached path)
        f32x4* xo = (f32x4*)Xout;
        const size_t base = (size_t)(bi * 256 + g * 16) * NV4 + (bj * 64 + c);
        #pragma unroll
        for (int r = 0; r < 16; ++r)
            xo[base + (size_t)r * NV4] = x[r];
    }
}

extern "C" void kernel_launch(void* const* d_in, const int* in_sizes, int n_in,
                              void* d_out, int out_size, void* d_ws, size_t ws_size,
                              hipStream_t stream)
{
    const float* X0 = (const float*)d_in[0];
    float* X = (float*)d_out;

    // ws: colF 1 MB | rowF 1 MB | gsB 32 KB  (contiguous, ~2.03 MB)
    u64* colF = (u64*)d_ws;
    u64* rowF = colF + 2 * NBLK * 256;
    u64* gsB  = rowF + 2 * NBLK * 256;

    // Memset ALL tagged arrays: kills stale 1..20 tags from a previous
    // launch (replay-safe: the memset is part of the captured stream;
    // harness 0xAA poison -> tag 0xAAAAAAAA never matches).
    const size_t tagged_bytes =
        (size_t)(2 * NBLK * 256 + 2 * NBLK * 256 + 2 * NBLK * 8) * sizeof(u64);
    hipMemsetAsync((void*)colF, 0, tagged_bytes, stream);

    // ~118.7 KB LDS -> 1 block/CU; grid == CU count -> all 256 blocks
    // co-resident (spin-waits are deadlock-free).
    persist14<<<dim3(NBLK), dim3(1024), 0, stream>>>(X0, X, colF, rowF, gsB);
}

// Round 8
// 258.689 us; speedup vs baseline: 1.2165x; 1.0788x over previous
//
#include <hip/hip_runtime.h>

// Frobenius — R17 (= R16 resubmit; round 7 bench died with an MI355X
// container/broker failure before producing any measurement or counters —
// kernel audit found no deadlock path, so the differential experiment is
// resubmitted verbatim).
//
// R16/R17: R13 (proven 160.4 us) with ONE isolated change: rowF
// publish+drain moved pre-A1 (per-wave), A2 deleted, flag after wave0's
// own colF drain.  Differential experiment isolating R12's phase-A shape
// from R12's slow phase B.
//
// Ladder: R9 181 -> R11 166.6 -> R13 160.4 (best).
// Regressions: R10 188, R12 200, R14 289, R15 206. R16: infra failure.
//
// LAWS (each confirmed by >=2 failures):
//  1. Poll density <=256 pollers/block, on dedicated 64B-spaced flag lines,
//     wave-uniform where possible. NEVER poll data words as the primary
//     wait (R10, R14, R15-retry).
//  2. A flag must be ack-ordered behind its data: store data ->
//     s_waitcnt vmcnt(0) (per-wave ok, collective ok) -> barrier covering
//     all producer waves -> flag. Relaxed stores to different lines have NO
//     cross-fabric visibility order (R15). No self-tagged shortcut.
//
// R17 phase A:
//   pre-A1 (all waves): cacc fold -> cqA; part transpose; row fold;
//     8 rowF pair-stores/wave; PER-WAVE s_waitcnt vmcnt(0)   [ack overlap]
//   A1  (now the release barrier for rowF: every wave ack'd before it)
//   wave0 only: col fold -> 2 colF stores -> bs butterfly (hides flight)
//     -> own vmcnt(0) -> lane0 flag (tag<<32 | bs).   Waves 1..15 skip
//     straight to phase-B polls.
// Phase B: R13 VERBATIM (fused fc/fr/fb poll, hoisted contiguous gathers
//   into LDS, loop-2 bsv, B0, redundant-fold tail).
// Barriers/iter: A1, B0.
//
// Deadlock audit (round 7): block j overwrites pflag[p][j] (tag k+1->k+3)
// only after B0(k+1), which required observing EVERY block's flag@k+2;
// a block publishes flag@k+2 only after consuming pflag[p][j]@k+1 ->
// exact-tag polls can never miss. Monotone, no ABA, spin-free-of-deadlock
// given co-residency (grid == 256 CUs, 1 block/CU via 117 KB LDS).
//
// WAR (parity double-buffer, unchanged transitive argument): writer's
// parity-p stores at iter k+2 follow its B0(k+1), which required observing
// every block's flag@k+2, each set after that block's A1(k+1), which its
// waves reach only after their iter-k gathers were consumed. Flag-gated
// reads -> colF/rowF need no init; memset only pflag (32 KB).

#define NN    4096
#define NV4   1024
#define NBLK  256
#define ITERS 20
#define INV_N (1.0f / 4096.0f)

typedef unsigned long long u64;
typedef float f32x4 __attribute__((ext_vector_type(4)));

__device__ __forceinline__ float wave_reduce_sum(float v) {
    #pragma unroll
    for (int m = 1; m < 64; m <<= 1) v += __shfl_xor(v, m, 64);
    return v;
}
__device__ __forceinline__ void st_b64(u64* p, u64 v) {
    __hip_atomic_store(p, v, __ATOMIC_RELAXED, __HIP_MEMORY_SCOPE_AGENT);
}
__device__ __forceinline__ u64 ld_b64(const u64* p) {
    return __hip_atomic_load(p, __ATOMIC_RELAXED, __HIP_MEMORY_SCOPE_AGENT);
}
__device__ __forceinline__ u64 packf2(float a, float b) {
    return (u64)__float_as_uint(a) | ((u64)__float_as_uint(b) << 32);
}
__device__ __forceinline__ float lo32(u64 u) { return __uint_as_float((unsigned)u); }
__device__ __forceinline__ float hi32(u64 u) { return __uint_as_float((unsigned)(u >> 32)); }

__global__ __launch_bounds__(1024, 4)
void persist16(const float* __restrict__ X0, float* __restrict__ Xout,
               u64* __restrict__ colF,    // [2][256][128] b64 = 2 packed f32
               u64* __restrict__ rowF,    // [2][256][128]
               u64* __restrict__ pflag)   // [2][256] stride-8 u64 (64 B apart)
{
    const int t    = threadIdx.x;
    const int lane = t & 63;
    const int g    = t >> 6;          // wave = 16-row group
    const int c    = lane;            // 4-col quad
    const int b    = blockIdx.x;
    const int bi   = b >> 4;
    const int bj   = b & 15;

    // 117 KB total -> 1 block/CU (grid == 256 == #CUs) -> co-residency.
    __shared__ float part[16][64][17];   // row-partial transpose (69.6 KB)
    __shared__ f32x4 cqA[16][64];        // phase-A col partials (16 KB)
    __shared__ f32x4 cqB[16][64];        // gathered col partials (16 KB)
    __shared__ f32x4 rqB[16][64];        // gathered row partials (16 KB)
    __shared__ float bsv[256];           // peer blocksums (1 KB)

    f32x4 x[16];
    {
        const f32x4* xi = (const f32x4*)X0;
        const size_t base = (size_t)(bi * 256 + g * 16) * NV4 + (bj * 64 + c);
        #pragma unroll
        for (int r = 0; r < 16; ++r)
            x[r] = xi[base + (size_t)r * NV4];
    }

    for (int iter = 0; iter < ITERS; ++iter) {
        const int p = iter & 1;
        const u64 tagv = (u64)(iter + 1);

        // ---- pre-A1 (all waves): partials, row fold, rowF publish+drain
        f32x4 cacc = x[0];
        #pragma unroll
        for (int r = 1; r < 16; ++r) cacc += x[r];
        cqA[g][c] = cacc;                             // per-wave col partial
        #pragma unroll
        for (int r = 0; r < 16; ++r)                  // bank-safe (17 pad)
            part[g][c][r] = (x[r].x + x[r].y) + (x[r].z + x[r].w);
        asm volatile("s_waitcnt lgkmcnt(0)" ::: "memory");  // wave-local LDS
        {   // row fold: wave g's 16 rows over 64 col-quads (LDS transpose)
            const int r_ = lane & 15, q_ = lane >> 4;
            float v = 0.f;
            #pragma unroll
            for (int k = 0; k < 16; ++k) v += part[g][q_ * 16 + k][r_];
            v += __shfl_xor(v, 16, 64);
            v += __shfl_xor(v, 32, 64);
            float vp = __shfl_xor(v, 1, 64);          // partner row value
            if (lane < 16 && (lane & 1) == 0)         // 8 b64 per wave
                st_b64(rowF + (((size_t)(p * NBLK + b)) << 7) + 8 * g + (lane >> 1),
                       packf2(v, vp));
        }
        asm volatile("s_waitcnt vmcnt(0)" ::: "memory");  // per-wave ack,
                                                          // overlapped
        __syncthreads();                              // A1: release barrier
                                                      // (all rowF ack'd)

        // ---- post-A1: ONLY wave0 on the flag edge (Law #2 kept: own drain)
        if (g == 0) {
            f32x4 vq = cqA[0][c];
            #pragma unroll
            for (int k = 1; k < 16; ++k) vq += cqA[k][c];
            u64* dst = colF + (((size_t)(p * NBLK + b)) << 7) + 2 * c;
            st_b64(dst,     packf2(vq.x, vq.y));
            st_b64(dst + 1, packf2(vq.z, vq.w));
            float bs = wave_reduce_sum((vq.x + vq.y) + (vq.z + vq.w));
            asm volatile("s_waitcnt vmcnt(0)" ::: "memory");  // colF ack'd
                                                              // (bs hid it)
            if (lane == 0)
                st_b64(pflag + ((size_t)(p * NBLK + b) << 3),
                       (tagv << 32) | (u64)__float_as_uint(bs));
        }

        // ---- phase B (R13 verbatim): fused poll + hoisted gather
        const int fcsrc = g * 16 + bj;    // col producer (wave-uniform)
        const int frsrc = bi * 16 + g;    // row producer (wave-uniform)
        {
            const u64* fc = pflag + ((size_t)(p * NBLK + fcsrc) << 3);
            const u64* fr = pflag + ((size_t)(p * NBLK + frsrc) << 3);
            const u64* fb = pflag + ((size_t)(p * NBLK + (t & 255)) << 3);
            bool dc = false, dr = false, db = (t >= 256);
            u64 ub = 0;
            // loop 1: wait for this wave's two producers (bsv opportunistic)
            while (!(dc && dr)) {
                if (!dc && (ld_b64(fc) >> 32) == tagv) dc = true;
                if (!dr && (ld_b64(fr) >> 32) == tagv) dr = true;
                if (!db) { u64 u = ld_b64(fb);
                           if ((u >> 32) == tagv) { ub = u; db = true; } }
                if (!(dc && dr)) __builtin_amdgcn_s_sleep(1);
            }
            asm volatile("" ::: "memory");
            {   // gather 1 KB/wave (contiguous), park in LDS
                const u64* cp = colF + (((size_t)(p * NBLK + fcsrc)) << 7) + 2 * c;
                const u64* rp = rowF + (((size_t)(p * NBLK + frsrc)) << 7) + 2 * c;
                u64 c0 = ld_b64(cp), c1 = ld_b64(cp + 1);
                u64 r0 = ld_b64(rp), r1 = ld_b64(rp + 1);
                f32x4 cv, rv;
                cv.x = lo32(c0); cv.y = hi32(c0); cv.z = lo32(c1); cv.w = hi32(c1);
                rv.x = lo32(r0); rv.y = hi32(r0); rv.z = lo32(r1); rv.w = hi32(r1);
                cqB[g][c] = cv;
                rqB[g][c] = rv;
            }
            // loop 2: finish the bsv poll (t<256 lanes only)
            while (!db) {
                u64 u = ld_b64(fb);
                if ((u >> 32) == tagv) { ub = u; db = true; }
                else __builtin_amdgcn_s_sleep(1);
            }
            if (t < 256) bsv[t] = lo32(ub);
        }
        asm volatile("" ::: "memory");
        __syncthreads();    // B0: all gathers in LDS, bsv complete

        // ---- tail (R13 verbatim): redundant per-wave/per-thread folds
        float vb = bsv[lane] + bsv[64 + lane] + bsv[128 + lane] + bsv[192 + lane];
        const float sG = wave_reduce_sum(vb);
        f32x4 cs = cqB[0][c];
        #pragma unroll
        for (int k = 1; k < 16; ++k) cs += cqB[k][c];
        float vr;
        {
            const int rr = lane & 15, kk = lane >> 4;
            const float* rqf = (const float*)&rqB[0][0];
            vr = 0.f;
            #pragma unroll
            for (int j = 0; j < 4; ++j)
                vr += rqf[(((4 * kk + j) * 64) + (4 * g + (rr >> 2))) * 4 + (rr & 3)];
            vr += __shfl_xor(vr, 16, 64);
            vr += __shfl_xor(vr, 32, 64);   // lane class rr holds rowsum[16g+rr]
        }

        const float cc0 = INV_N + sG * (INV_N * INV_N);
        const f32x4 csub = cs * INV_N;
        #pragma unroll
        for (int r = 0; r < 16; ++r) {
            const float rwr = __shfl(vr, r, 64);      // rowsum[16g+r]
            const float a = cc0 - rwr * INV_N;
            x[r].x = fmaxf(x[r].x + a - csub.x, 0.f);
            x[r].y = fmaxf(x[r].y + a - csub.y, 0.f);
            x[r].z = fmaxf(x[r].z + a - csub.z, 0.f);
            x[r].w = fmaxf(x[r].w + a - csub.w, 0.f);
        }
        // LDS reuse: iter-k tail reads precede A1(k+1) per thread; cqA(k+1)
        // writers passed B0(k) first; cqB/rqB/bsv(k+1) writes are
        // post-A1(k+1); part is wave-local -> race-free.
    }

    {   // final store (plain cached path)
        f32x4* xo = (f32x4*)Xout;
        const size_t base = (size_t)(bi * 256 + g * 16) * NV4 + (bj * 64 + c);
        #pragma unroll
        for (int r = 0; r < 16; ++r)
            xo[base + (size_t)r * NV4] = x[r];
    }
}

extern "C" void kernel_launch(void* const* d_in, const int* in_sizes, int n_in,
                              void* d_out, int out_size, void* d_ws, size_t ws_size,
                              hipStream_t stream)
{
    const float* X0 = (const float*)d_in[0];
    float* X = (float*)d_out;

    // ws: colF 512 KB | rowF 512 KB | pflag 32 KB   (~1.06 MB)
    u64* colF  = (u64*)d_ws;
    u64* rowF  = colF + 2 * NBLK * 128;
    u64* pflag = rowF + 2 * NBLK * 128;

    // Only flags need zeroing: data reads are flag-gated, flags are
    // exact-tag -> poison/stale words can never satisfy a poll.
    hipMemsetAsync((void*)pflag, 0, 2 * NBLK * 8 * sizeof(u64), stream);

    // 117 KB LDS -> 1 block/CU; grid == CU count -> all 256 blocks
    // co-resident (spin-waits are deadlock-free).
    persist16<<<dim3(NBLK), dim3(1024), 0, stream>>>(X0, X, colF, rowF, pflag);
}

// Round 9
// 239.725 us; speedup vs baseline: 1.3127x; 1.0791x over previous
//
#include <hip/hip_runtime.h>

// Frobenius — R18: R13 (proven 160.4 us) with phase A + sync FROZEN;
// only the phase-B gather/tail changed: pre-fold depth 2 during gather,
// tail folds 8-deep, row path via broadcast v4 reads (kills 655K conflicts).
//
// Ladder: R9 181 -> R11 166.6 -> R13 160.4 (best).
// Regressions: R10 188, R12 200, R14 289, R15 206, R17 178.
//
// LAWS (each confirmed by >=2 failed experiments):
//  1. Poll density <=256 pollers/block on dedicated 64B-spaced flag lines,
//     wave-uniform where possible. NEVER poll data words as primary wait
//     (R10, R14, R15).
//  2. A flag must be ack-ordered behind its data: data stores ->
//     s_waitcnt vmcnt(0) -> barrier over producer waves -> flag. Relaxed
//     stores to different lines have NO cross-fabric visibility order (R15).
//  3. The remote-store ack (~1 us) on the flag edge must be OVERLAPPED with
//     other waves' parallel work (R13's A1..A2 window). A lone wave
//     draining its own stores serializes it (R12 +1.6, R17 +0.9 us/iter).
//     => R13's phase A is change-frozen.
//
// R18 phase B: waves 0..7 gather col peers {32w+bj, 32w+16+bj}; waves 8..15
// gather row peers {bi*16+2w', +1}. Each: poll 2 wave-uniform flags, 4 b64
// loads, 1 v4 reg-fold, park 1 LDS entry. bsv pollers (t<256) unchanged.
// Tail: col = 8 consecutive v4 reads + 7 adds; row = 8 broadcast v4 reads
// (lane-quads share addresses -> no conflicts) + 7 adds + 16 shfl bcasts.
//
// WAR (parity double-buffer, unchanged transitive argument): writer's
// parity-p stores at iter k+2 follow observing every flag@k+1 (B-phase
// polls collectively cover all 256 flags), each set after that block's
// A2(k+1), which follows its iter-k gathers. Flag-gated reads -> colF/rowF
// need no init; memset only pflag (32 KB).

#define NN    4096
#define NV4   1024
#define NBLK  256
#define ITERS 20
#define INV_N (1.0f / 4096.0f)

typedef unsigned long long u64;
typedef float f32x4 __attribute__((ext_vector_type(4)));

__device__ __forceinline__ float wave_reduce_sum(float v) {
    #pragma unroll
    for (int m = 1; m < 64; m <<= 1) v += __shfl_xor(v, m, 64);
    return v;
}
__device__ __forceinline__ void st_b64(u64* p, u64 v) {
    __hip_atomic_store(p, v, __ATOMIC_RELAXED, __HIP_MEMORY_SCOPE_AGENT);
}
__device__ __forceinline__ u64 ld_b64(const u64* p) {
    return __hip_atomic_load(p, __ATOMIC_RELAXED, __HIP_MEMORY_SCOPE_AGENT);
}
__device__ __forceinline__ u64 packf2(float a, float b) {
    return (u64)__float_as_uint(a) | ((u64)__float_as_uint(b) << 32);
}
__device__ __forceinline__ float lo32(u64 u) { return __uint_as_float((unsigned)u); }
__device__ __forceinline__ float hi32(u64 u) { return __uint_as_float((unsigned)(u >> 32)); }

__global__ __launch_bounds__(1024, 4)
void persist17(const float* __restrict__ X0, float* __restrict__ Xout,
               u64* __restrict__ colF,    // [2][256][128] b64 = 2 packed f32
               u64* __restrict__ rowF,    // [2][256][128]
               u64* __restrict__ pflag)   // [2][256] stride-8 u64 (64 B apart)
{
    const int t    = threadIdx.x;
    const int lane = t & 63;
    const int g    = t >> 6;          // wave = 16-row group
    const int c    = lane;            // 4-col quad
    const int b    = blockIdx.x;
    const int bi   = b >> 4;
    const int bj   = b & 15;

    // ~101 KB -> 1 block/CU (grid == 256 == #CUs) -> co-residency.
    __shared__ float part[16][64][17];   // row-partial transpose (69.6 KB)
    __shared__ f32x4 cqA[16][64];        // phase-A col partials (16 KB)
    __shared__ f32x4 cqB[8][64];         // gathered col partials, depth-2 (8 KB)
    __shared__ f32x4 rqB[8][64];         // gathered row partials, depth-2 (8 KB)
    __shared__ float bsv[256];           // peer blocksums (1 KB)

    f32x4 x[16];
    {
        const f32x4* xi = (const f32x4*)X0;
        const size_t base = (size_t)(bi * 256 + g * 16) * NV4 + (bj * 64 + c);
        #pragma unroll
        for (int r = 0; r < 16; ++r)
            x[r] = xi[base + (size_t)r * NV4];
    }

    for (int iter = 0; iter < ITERS; ++iter) {
        const int p = iter & 1;
        const u64 tagv = (u64)(iter + 1);

        // ---- phase A (R13 verbatim — FROZEN): partials, publish, drain, flag
        f32x4 cacc = x[0];
        #pragma unroll
        for (int r = 1; r < 16; ++r) cacc += x[r];
        cqA[g][c] = cacc;                             // per-wave col partial
        #pragma unroll
        for (int r = 0; r < 16; ++r)                  // bank-safe (17 pad)
            part[g][c][r] = (x[r].x + x[r].y) + (x[r].z + x[r].w);
        __syncthreads();                              // A1

        float bs = 0.f;
        if (g == 0) {   // fold 16 waves' col partials, publish 256 cols
            f32x4 vq = cqA[0][c];
            #pragma unroll
            for (int k = 1; k < 16; ++k) vq += cqA[k][c];
            u64* dst = colF + (((size_t)(p * NBLK + b)) << 7) + 2 * c;
            st_b64(dst,     packf2(vq.x, vq.y));
            st_b64(dst + 1, packf2(vq.z, vq.w));
            bs = wave_reduce_sum((vq.x + vq.y) + (vq.z + vq.w));
        }
        {   // row fold: wave g's 16 rows over 64 col-quads (LDS transpose)
            const int r_ = lane & 15, q_ = lane >> 4;
            float v = 0.f;
            #pragma unroll
            for (int k = 0; k < 16; ++k) v += part[g][q_ * 16 + k][r_];
            v += __shfl_xor(v, 16, 64);
            v += __shfl_xor(v, 32, 64);
            float vp = __shfl_xor(v, 1, 64);          // partner row value
            if (lane < 16 && (lane & 1) == 0)         // 8 b64 per wave
                st_b64(rowF + (((size_t)(p * NBLK + b)) << 7) + 8 * g + (lane >> 1),
                       packf2(v, vp));
        }
        asm volatile("s_waitcnt vmcnt(0)" ::: "memory");  // all stores acked
        __syncthreads();                                  // A2: block drained
        if (t == 0)
            st_b64(pflag + ((size_t)(p * NBLK + b) << 3),
                   (tagv << 32) | (u64)__float_as_uint(bs));

        // ---- phase B: split gather waves, pre-fold depth 2
        if (g < 8) {        // col gather: peers 2g, 2g+1 of column band bj
            const int p0 = 32 * g + bj, p1 = 32 * g + 16 + bj;
            const u64* f0 = pflag + ((size_t)(p * NBLK + p0) << 3);
            const u64* f1 = pflag + ((size_t)(p * NBLK + p1) << 3);
            const u64* fb = pflag + ((size_t)(p * NBLK + (t & 255)) << 3);
            bool d0 = false, d1 = false, db = (t >= 256);
            u64 ub = 0;
            while (!(d0 && d1)) {
                if (!d0 && (ld_b64(f0) >> 32) == tagv) d0 = true;
                if (!d1 && (ld_b64(f1) >> 32) == tagv) d1 = true;
                if (!db) { u64 u = ld_b64(fb);
                           if ((u >> 32) == tagv) { ub = u; db = true; } }
                if (!(d0 && d1)) __builtin_amdgcn_s_sleep(1);
            }
            asm volatile("" ::: "memory");
            {   // 4 b64 loads (2 peers), reg-fold, park 1 entry
                const u64* c0p = colF + (((size_t)(p * NBLK + p0)) << 7) + 2 * c;
                const u64* c1p = colF + (((size_t)(p * NBLK + p1)) << 7) + 2 * c;
                u64 a0 = ld_b64(c0p), a1 = ld_b64(c0p + 1);
                u64 b0 = ld_b64(c1p), b1 = ld_b64(c1p + 1);
                f32x4 cv;
                cv.x = lo32(a0) + lo32(b0); cv.y = hi32(a0) + hi32(b0);
                cv.z = lo32(a1) + lo32(b1); cv.w = hi32(a1) + hi32(b1);
                cqB[g][c] = cv;
            }
            while (!db) {   // finish bsv poll (waves 0..3 lanes)
                u64 u = ld_b64(fb);
                if ((u >> 32) == tagv) { ub = u; db = true; }
                else __builtin_amdgcn_s_sleep(1);
            }
            if (t < 256) bsv[t] = lo32(ub);
        } else {            // row gather: peers 2w', 2w'+1 of row band bi
            const int w = g - 8;
            const int q0 = bi * 16 + 2 * w, q1 = q0 + 1;
            const u64* f0 = pflag + ((size_t)(p * NBLK + q0) << 3);
            const u64* f1 = pflag + ((size_t)(p * NBLK + q1) << 3);
            bool d0 = false, d1 = false;
            while (!(d0 && d1)) {
                if (!d0 && (ld_b64(f0) >> 32) == tagv) d0 = true;
                if (!d1 && (ld_b64(f1) >> 32) == tagv) d1 = true;
                if (!(d0 && d1)) __builtin_amdgcn_s_sleep(1);
            }
            asm volatile("" ::: "memory");
            const u64* r0p = rowF + (((size_t)(p * NBLK + q0)) << 7) + 2 * c;
            const u64* r1p = rowF + (((size_t)(p * NBLK + q1)) << 7) + 2 * c;
            u64 a0 = ld_b64(r0p), a1 = ld_b64(r0p + 1);
            u64 b0 = ld_b64(r1p), b1 = ld_b64(r1p + 1);
            f32x4 rv;
            rv.x = lo32(a0) + lo32(b0); rv.y = hi32(a0) + hi32(b0);
            rv.z = lo32(a1) + lo32(b1); rv.w = hi32(a1) + hi32(b1);
            rqB[w][c] = rv;
        }
        asm volatile("" ::: "memory");
        __syncthreads();    // B0: all pre-folded gathers in LDS, bsv complete

        // ---- tail: 8-deep folds (was 16), conflict-free row path
        float vb = bsv[lane] + bsv[64 + lane] + bsv[128 + lane] + bsv[192 + lane];
        const float sG = wave_reduce_sum(vb);         // identical all blocks
        f32x4 cs = cqB[0][c];
        #pragma unroll
        for (int k = 1; k < 8; ++k) cs += cqB[k][c];  // consecutive v4: free
        f32x4 rq4 = rqB[0][4 * g + (lane & 3)];       // broadcast within quads
        #pragma unroll
        for (int k = 1; k < 8; ++k) rq4 += rqB[k][4 * g + (lane & 3)];
        const float rqa[4] = {rq4.x, rq4.y, rq4.z, rq4.w};

        const float cc0 = INV_N + sG * (INV_N * INV_N);
        const f32x4 csub = cs * INV_N;
        #pragma unroll
        for (int r = 0; r < 16; ++r) {
            // rowsum[16g+r] = component r&3 of lane (r>>2)'s folded quad
            const float rwr = __shfl(rqa[r & 3], r >> 2, 64);
            const float a = cc0 - rwr * INV_N;
            x[r].x = fmaxf(x[r].x + a - csub.x, 0.f);
            x[r].y = fmaxf(x[r].y + a - csub.y, 0.f);
            x[r].z = fmaxf(x[r].z + a - csub.z, 0.f);
            x[r].w = fmaxf(x[r].w + a - csub.w, 0.f);
        }
        // LDS reuse: iter-k tail reads precede A1(k+1) per thread; cqA(k+1)
        // writers passed B0(k) first; cqB/rqB/bsv(k+1) writes are
        // post-A2(k+1); part is wave-local -> race-free.
    }

    {   // final store (plain cached path)
        f32x4* xo = (f32x4*)Xout;
        const size_t base = (size_t)(bi * 256 + g * 16) * NV4 + (bj * 64 + c);
        #pragma unroll
        for (int r = 0; r < 16; ++r)
            xo[base + (size_t)r * NV4] = x[r];
    }
}

extern "C" void kernel_launch(void* const* d_in, const int* in_sizes, int n_in,
                              void* d_out, int out_size, void* d_ws, size_t ws_size,
                              hipStream_t stream)
{
    const float* X0 = (const float*)d_in[0];
    float* X = (float*)d_out;

    // ws: colF 512 KB | rowF 512 KB | pflag 32 KB   (~1.06 MB)
    u64* colF  = (u64*)d_ws;
    u64* rowF  = colF + 2 * NBLK * 128;
    u64* pflag = rowF + 2 * NBLK * 128;

    // Only flags need zeroing: data reads are flag-gated, flags are
    // exact-tag -> poison/stale words can never satisfy a poll.
    hipMemsetAsync((void*)pflag, 0, 2 * NBLK * 8 * sizeof(u64), stream);

    // ~101 KB LDS -> 1 block/CU; grid == CU count -> all 256 blocks
    // co-resident (spin-waits are deadlock-free).
    persist17<<<dim3(NBLK), dim3(1024), 0, stream>>>(X0, X, colF, rowF, pflag);
}